// Round 12
// baseline (99.115 us; speedup 1.0000x reference)
//
#include <hip/hip_runtime.h>
#include <float.h>
#include <limits.h>

typedef __attribute__((ext_vector_type(4))) int int4v;

#define N_E   1024
#define E_DIM 256
#define N_TOKS 65536

#define SZF 21.166666f            // 127/6  (z scale, clamp at 6 sigma)
#define SEF 130048.0f             // 127*1024 (emb scale; |emb|<=1/1024)
#define ABSC2F (2.0f / (21.166666f * 130048.0f))   // s_real = s_int * ABSC2F

#define TILE_B 4160               // 4096 i8 payload + 64 B en row

// ---------------------------------------------------------------------------
// Prep: emb fp32 -> i8 B-frag tiles WITH appended en_int row per tile.
// ---------------------------------------------------------------------------
__global__ __launch_bounds__(256) void vq_prep(const float* __restrict__ emb,
                                               signed char* __restrict__ embT) {
  const int code = blockIdx.x;
  const int t    = threadIdx.x;
  float v = emb[(size_t)code * E_DIM + t];
  int q = __float2int_rn(v * SEF);
  q = q > 127 ? 127 : (q < -127 ? -127 : q);
  const int m = t >> 6, kq = (t >> 4) & 3, j = t & 15;
  embT[(size_t)(code >> 4) * TILE_B + m * 1024 + kq * 256 + (code & 15) * 16 + j] =
      (signed char)q;
  float sq = v * v;
  #pragma unroll
  for (int s = 1; s < 64; s <<= 1) sq += __shfl_xor(sq, s);
  __shared__ float ws3[4];
  if ((t & 63) == 0) ws3[t >> 6] = sq;
  __syncthreads();
  if (t == 0)
    *(int*)(embT + (size_t)(code >> 4) * TILE_B + 4096 + (code & 15) * 4) =
        __float2int_rn((ws3[0] + ws3[1] + ws3[2] + ws3[3]) / ABSC2F);
}

// ---- shared helpers as macros (textual identity across the 3 kernels) ------
#define ZPHASE_DECL                                                            \
  int4v a[2][4];                                                               \
  _Pragma("unroll")                                                            \
  for (int g = 0; g < 2; ++g) {                                                \
    const float* zp = z + (size_t)(blk * 128 + wv * 32 + g * 16 + lrow) * E_DIM + lk * 16; \
    float zn = 0.f;                                                            \
    _Pragma("unroll")                                                          \
    for (int m = 0; m < 4; ++m) {                                              \
      int4v pk;                                                                \
      _Pragma("unroll")                                                        \
      for (int d = 0; d < 4; ++d) {                                            \
        float4 f = *(const float4*)(zp + m * 64 + d * 4);                      \
        zn += f.x * f.x + f.y * f.y + f.z * f.z + f.w * f.w;                   \
        int q0 = __float2int_rn(fminf(fmaxf(f.x * -SZF, -127.f), 127.f));      \
        int q1 = __float2int_rn(fminf(fmaxf(f.y * -SZF, -127.f), 127.f));      \
        int q2 = __float2int_rn(fminf(fmaxf(f.z * -SZF, -127.f), 127.f));      \
        int q3 = __float2int_rn(fminf(fmaxf(f.w * -SZF, -127.f), 127.f));      \
        pk[d] = (q0 & 255) | ((q1 & 255) << 8) | ((q2 & 255) << 16) | ((q3 & 255) << 24); \
      }                                                                        \
      a[g][m] = pk;                                                            \
    }                                                                          \
    zn += __shfl_xor(zn, 16);                                                  \
    zn += __shfl_xor(zn, 32);                                                  \
    if (lk == 0) znl[wv * 32 + g * 16 + lrow] = zn;                            \
  }

#define TIX(i) ((st + (i)) & 63)
#define BLOAD(dst, enr, T) do {                                                \
    const signed char* p_ = embT + (size_t)(T) * TILE_B + lane * 16;           \
    dst[0] = *(const int4v*)(p_);                                              \
    dst[1] = *(const int4v*)(p_ + 1024);                                       \
    dst[2] = *(const int4v*)(p_ + 2048);                                       \
    dst[3] = *(const int4v*)(p_ + 3072);                                       \
    enr    = *(const int*)(embT + (size_t)(T) * TILE_B + 4096 + lrow * 4);     \
  } while (0)
#define WAITV(n) asm volatile("s_waitcnt vmcnt(" #n ")" ::: "memory")

// ---------------------------------------------------------------------------
// REAL kernel: 512 blocks x 4 indep waves, 32 tok/wave, 4-deep ring, fused.
// ---------------------------------------------------------------------------
__global__ __launch_bounds__(256, 2) void vq_main(
    const float* __restrict__ z, const signed char* __restrict__ embT,
    const float* __restrict__ emb,
    float* __restrict__ out, float* __restrict__ partials) {
  __shared__ float znl[128];
  __shared__ int   keyl[128];
  const int tid = threadIdx.x, lane = tid & 63, wv = tid >> 6;
  const int blk = blockIdx.x, lrow = lane & 15, lk = lane >> 4;
  const int st  = (blk * 37) & 63;

  ZPHASE_DECL

  int4v b0[4], b1[4], b2[4], b3[4];
  int   e0, e1, e2, e3;
  BLOAD(b0, e0, TIX(0)); BLOAD(b1, e1, TIX(1));
  BLOAD(b2, e2, TIX(2)); BLOAD(b3, e3, TIX(3));

  int bk[2][4];
  #pragma unroll
  for (int r = 0; r < 4; ++r) { bk[0][r] = INT_MAX; bk[1][r] = INT_MAX; }

#define COMPUTE(b, enr, T) do {                                                \
    int4v ci = {enr, enr, enr, enr};                                           \
    int4v ac0 = ci, ac1 = ci;                                                  \
    _Pragma("unroll")                                                          \
    for (int m_ = 0; m_ < 4; ++m_) {                                           \
      ac0 = __builtin_amdgcn_mfma_i32_16x16x64_i8(a[0][m_], b[m_], ac0, 0, 0, 0);\
      ac1 = __builtin_amdgcn_mfma_i32_16x16x64_i8(a[1][m_], b[m_], ac1, 0, 0, 0);\
    }                                                                          \
    const int cd_ = (T) * 16 + lrow;                                           \
    _Pragma("unroll")                                                          \
    for (int r_ = 0; r_ < 4; ++r_) {                                           \
      bk[0][r_] = min(bk[0][r_], ((ac0[r_] >> 2) << 10) | cd_);                \
      bk[1][r_] = min(bk[1][r_], ((ac1[r_] >> 2) << 10) | cd_);                \
    }                                                                          \
  } while (0)

  for (int it = 0; it < 60; it += 4) {
    WAITV(15); COMPUTE(b0, e0, TIX(it + 0)); if (it < 56) BLOAD(b0, e0, TIX(it + 4));
    WAITV(15); COMPUTE(b1, e1, TIX(it + 1)); if (it < 56) BLOAD(b1, e1, TIX(it + 5));
    WAITV(15); COMPUTE(b2, e2, TIX(it + 2)); if (it < 56) BLOAD(b2, e2, TIX(it + 6));
    WAITV(15); COMPUTE(b3, e3, TIX(it + 3)); if (it < 56) BLOAD(b3, e3, TIX(it + 7));
  }
  WAITV(15); COMPUTE(b0, e0, TIX(60));
  WAITV(10); COMPUTE(b1, e1, TIX(61));
  WAITV(5);  COMPUTE(b2, e2, TIX(62));
  WAITV(0);  COMPUTE(b3, e3, TIX(63));
#undef COMPUTE

  #pragma unroll
  for (int m = 1; m < 16; m <<= 1)
    #pragma unroll
    for (int g = 0; g < 2; ++g)
      #pragma unroll
      for (int r = 0; r < 4; ++r)
        bk[g][r] = min(bk[g][r], __shfl_xor(bk[g][r], m));
  if (lrow == 0)
    #pragma unroll
    for (int g = 0; g < 2; ++g)
      #pragma unroll
      for (int r = 0; r < 4; ++r)
        keyl[wv * 32 + g * 16 + lk * 4 + r] = bk[g][r];

  const float4* emb4 = (const float4*)emb;
  float4*       out4 = (float4*)out;
  const size_t outBase = (size_t)blk * 128 + wv * 32;
  #pragma unroll 8
  for (int t2 = 0; t2 < 32; ++t2) {
    const int ci = keyl[wv * 32 + t2] & 1023;
    out4[(outBase + t2) * 64 + lane] = emb4[(size_t)ci * 64 + lane];
  }

  const int tok = wv * 32 + (lane & 31);
  const int key = keyl[tok];
  const float sbest = (float)((key >> 10) << 2) * ABSC2F;
  float lt = (znl[tok] + sbest) * 0.5f;
  #pragma unroll
  for (int m = 1; m < 64; m <<= 1) lt += __shfl_xor(lt, m);
  if (lane == 0) partials[blk * 4 + wv] = lt;
}

// ---------------------------------------------------------------------------
// ABLATION M: loads/waits/z-phase identical, MFMA+key replaced by adds.
// ---------------------------------------------------------------------------
__global__ __launch_bounds__(256, 2) void vq_abM(
    const float* __restrict__ z, const signed char* __restrict__ embT,
    int* __restrict__ sink) {
  __shared__ float znl[128];
  const int tid = threadIdx.x, lane = tid & 63, wv = tid >> 6;
  const int blk = blockIdx.x, lrow = lane & 15, lk = lane >> 4;
  const int st  = (blk * 37) & 63;

  ZPHASE_DECL

  int4v b0[4], b1[4], b2[4], b3[4];
  int   e0, e1, e2, e3;
  BLOAD(b0, e0, TIX(0)); BLOAD(b1, e1, TIX(1));
  BLOAD(b2, e2, TIX(2)); BLOAD(b3, e3, TIX(3));

  int4v acc = {0, 0, 0, 0};
  #pragma unroll
  for (int g = 0; g < 2; ++g)
    #pragma unroll
    for (int m = 0; m < 4; ++m) acc += a[g][m];   // keep quantize live

#define CONSUME(b, enr) do {                                                   \
    acc += b[0]; acc += b[1]; acc += b[2]; acc += b[3];                        \
    acc[0] += enr;                                                             \
  } while (0)

  for (int it = 0; it < 60; it += 4) {
    WAITV(15); CONSUME(b0, e0); if (it < 56) BLOAD(b0, e0, TIX(it + 4));
    WAITV(15); CONSUME(b1, e1); if (it < 56) BLOAD(b1, e1, TIX(it + 5));
    WAITV(15); CONSUME(b2, e2); if (it < 56) BLOAD(b2, e2, TIX(it + 6));
    WAITV(15); CONSUME(b3, e3); if (it < 56) BLOAD(b3, e3, TIX(it + 7));
  }
  WAITV(15); CONSUME(b0, e0);
  WAITV(10); CONSUME(b1, e1);
  WAITV(5);  CONSUME(b2, e2);
  WAITV(0);  CONSUME(b3, e3);
#undef CONSUME

  sink[(size_t)blk * 256 + tid] =
      acc[0] + acc[1] + acc[2] + acc[3] + (int)znl[wv * 32 + lrow];
}

// ---------------------------------------------------------------------------
// ABLATION C: one ring fill, 64 compute steps (no in-loop loads/waits).
// CSE defeated: acc init = enr + step.
// ---------------------------------------------------------------------------
__global__ __launch_bounds__(256, 2) void vq_abC(
    const float* __restrict__ z, const signed char* __restrict__ embT,
    int* __restrict__ keysink) {
  __shared__ float znl[128];
  const int tid = threadIdx.x, lane = tid & 63, wv = tid >> 6;
  const int blk = blockIdx.x, lrow = lane & 15, lk = lane >> 4;
  const int st  = (blk * 37) & 63;

  ZPHASE_DECL

  int4v b0[4], b1[4], b2[4], b3[4];
  int   e0, e1, e2, e3;
  BLOAD(b0, e0, TIX(0)); BLOAD(b1, e1, TIX(1));
  BLOAD(b2, e2, TIX(2)); BLOAD(b3, e3, TIX(3));
  WAITV(0);

  int bk[2][4];
  #pragma unroll
  for (int r = 0; r < 4; ++r) { bk[0][r] = INT_MAX; bk[1][r] = INT_MAX; }

#define COMPUTEC(b, enr, T, S) do {                                            \
    int ebase = enr + (S);                                                     \
    int4v ci = {ebase, ebase, ebase, ebase};                                   \
    int4v ac0 = ci, ac1 = ci;                                                  \
    _Pragma("unroll")                                                          \
    for (int m_ = 0; m_ < 4; ++m_) {                                           \
      ac0 = __builtin_amdgcn_mfma_i32_16x16x64_i8(a[0][m_], b[m_], ac0, 0, 0, 0);\
      ac1 = __builtin_amdgcn_mfma_i32_16x16x64_i8(a[1][m_], b[m_], ac1, 0, 0, 0);\
    }                                                                          \
    const int cd_ = (T) * 16 + lrow;                                           \
    _Pragma("unroll")                                                          \
    for (int r_ = 0; r_ < 4; ++r_) {                                           \
      bk[0][r_] = min(bk[0][r_], ((ac0[r_] >> 2) << 10) | cd_);                \
      bk[1][r_] = min(bk[1][r_], ((ac1[r_] >> 2) << 10) | cd_);                \
    }                                                                          \
  } while (0)

  for (int it = 0; it < 64; it += 4) {
    COMPUTEC(b0, e0, TIX(it + 0), it);
    COMPUTEC(b1, e1, TIX(it + 1), it + 1);
    COMPUTEC(b2, e2, TIX(it + 2), it + 2);
    COMPUTEC(b3, e3, TIX(it + 3), it + 3);
  }
#undef COMPUTEC

  #pragma unroll
  for (int m = 1; m < 16; m <<= 1)
    #pragma unroll
    for (int g = 0; g < 2; ++g)
      #pragma unroll
      for (int r = 0; r < 4; ++r)
        bk[g][r] = min(bk[g][r], __shfl_xor(bk[g][r], m));
  if (lrow == 0)
    #pragma unroll
    for (int g = 0; g < 2; ++g)
      #pragma unroll
      for (int r = 0; r < 4; ++r)
        keysink[blk * 128 + wv * 32 + g * 16 + lk * 4 + r] =
            bk[g][r] + (int)znl[wv * 32 + lk];
}

// ---------------------------------------------------------------------------
// Final deterministic loss reduction: 2048 partials -> scalar
// ---------------------------------------------------------------------------
__global__ __launch_bounds__(256) void vq_loss(const float* __restrict__ partials,
                                               float* __restrict__ lossOut) {
  const int tid = threadIdx.x;
  float v = 0.f;
  #pragma unroll
  for (int i = 0; i < 8; ++i) v += partials[tid + i * 256];
  #pragma unroll
  for (int m = 1; m < 64; m <<= 1) v += __shfl_xor(v, m);
  __shared__ float ws2[4];
  if ((tid & 63) == 0) ws2[tid >> 6] = v;
  __syncthreads();
  if (tid == 0)
    lossOut[0] = (ws2[0] + ws2[1] + ws2[2] + ws2[3]) * (1.25f / 16777216.f);
}

extern "C" void kernel_launch(void* const* d_in, const int* in_sizes, int n_in,
                              void* d_out, int out_size, void* d_ws, size_t ws_size,
                              hipStream_t stream) {
  const float* z   = (const float*)d_in[0];
  const float* emb = (const float*)d_in[1];
  float* out = (float*)d_out;

  char* ws = (char*)d_ws;
  signed char* embT   = (signed char*)ws;              // 266240 B
  float*       parts  = (float*)(ws + (272 << 10));    // 8 KB
  int*         abMs   = (int*)  (ws + (320 << 10));    // 512 KB
  int*         abCk   = (int*)  (ws + (896 << 10));    // 256 KB

  vq_prep<<<N_E, 256, 0, stream>>>(emb, embT);
  vq_abM<<<N_TOKS / 128, 256, 0, stream>>>(z, embT, abMs);
  vq_abC<<<N_TOKS / 128, 256, 0, stream>>>(z, embT, abCk);
  vq_main<<<N_TOKS / 128, 256, 0, stream>>>(z, embT, emb, out, parts);
  vq_loss<<<1, 256, 0, stream>>>(parts, out + (size_t)N_TOKS * E_DIM);
}

// Round 13
// 48.276 us; speedup vs baseline: 2.0531x; 2.0531x over previous
//
#include <hip/hip_runtime.h>
#include <float.h>
#include <limits.h>

typedef __attribute__((ext_vector_type(4))) int int4v;

#define N_E   1024
#define E_DIM 256
#define N_TOKS 65536

#define SZF 21.166666f            // 127/6  (z scale, clamp at 6 sigma)
#define SEF 130048.0f             // 127*1024 (emb scale; |emb|<=1/1024)
#define ABSC2F (2.0f / (21.166666f * 130048.0f))   // s_real = s_int * ABSC2F

#define TILE_B 4160               // 4096 i8 payload + 64 B en row

// ---------------------------------------------------------------------------
// Prep: emb fp32 -> i8 B-frag tiles WITH appended en_int row per tile.
// payload byte = tile*4160 + m*1024 + kq*256 + c*16 + j   (k = m*64+kq*16+j)
// ---------------------------------------------------------------------------
__global__ __launch_bounds__(256) void vq_prep(const float* __restrict__ emb,
                                               signed char* __restrict__ embT) {
  const int code = blockIdx.x;
  const int t    = threadIdx.x;
  float v = emb[(size_t)code * E_DIM + t];
  int q = __float2int_rn(v * SEF);
  q = q > 127 ? 127 : (q < -127 ? -127 : q);
  const int m = t >> 6, kq = (t >> 4) & 3, j = t & 15;
  embT[(size_t)(code >> 4) * TILE_B + m * 1024 + kq * 256 + (code & 15) * 16 + j] =
      (signed char)q;
  float sq = v * v;
  #pragma unroll
  for (int s = 1; s < 64; s <<= 1) sq += __shfl_xor(sq, s);
  __shared__ float ws3[4];
  if ((t & 63) == 0) ws3[t >> 6] = sq;
  __syncthreads();
  if (t == 0)
    *(int*)(embT + (size_t)(code >> 4) * TILE_B + 4096 + (code & 15) * 4) =
        __float2int_rn((ws3[0] + ws3[1] + ws3[2] + ws3[3]) / ABSC2F);
}

// ---------------------------------------------------------------------------
// Main: 512 blocks x 4 indep waves (zero barriers), 32 tok/wave, 4-phase
// register ring. K-SPLIT accumulators: per token-group two 2-deep MFMA
// chains (p init=en, q init=0, combined by one v_add) -> 4 independent
// chains/wave = 8 streams/SIMD to cover MFMA latency.
// st aligned across co-resident blocks (blk&255) for L1 tile sharing.
// ---------------------------------------------------------------------------
__global__ __launch_bounds__(256, 2) void vq_main(
    const float* __restrict__ z, const signed char* __restrict__ embT,
    const float* __restrict__ emb,
    float* __restrict__ out, float* __restrict__ partials) {
  __shared__ float znl[128];
  __shared__ int   keyl[128];
  const int tid = threadIdx.x, lane = tid & 63, wv = tid >> 6;
  const int blk = blockIdx.x, lrow = lane & 15, lk = lane >> 4;
  const int st  = ((blk & 255) * 37) & 63;

  // ---- z -> negated i8 A-frags + exact fp32 znorm --------------------------
  int4v a[2][4];
  #pragma unroll
  for (int g = 0; g < 2; ++g) {
    const float* zp = z + (size_t)(blk * 128 + wv * 32 + g * 16 + lrow) * E_DIM + lk * 16;
    float zn = 0.f;
    #pragma unroll
    for (int m = 0; m < 4; ++m) {
      int4v pk;
      #pragma unroll
      for (int d = 0; d < 4; ++d) {
        float4 f = *(const float4*)(zp + m * 64 + d * 4);
        zn += f.x * f.x + f.y * f.y + f.z * f.z + f.w * f.w;
        int q0 = __float2int_rn(fminf(fmaxf(f.x * -SZF, -127.f), 127.f));
        int q1 = __float2int_rn(fminf(fmaxf(f.y * -SZF, -127.f), 127.f));
        int q2 = __float2int_rn(fminf(fmaxf(f.z * -SZF, -127.f), 127.f));
        int q3 = __float2int_rn(fminf(fmaxf(f.w * -SZF, -127.f), 127.f));
        pk[d] = (q0 & 255) | ((q1 & 255) << 8) | ((q2 & 255) << 16) | ((q3 & 255) << 24);
      }
      a[g][m] = pk;
    }
    zn += __shfl_xor(zn, 16);
    zn += __shfl_xor(zn, 32);
    if (lk == 0) znl[wv * 32 + g * 16 + lrow] = zn;
  }

#define TIX(i) ((st + (i)) & 63)
#define BLOAD(dst, enr, T) do {                                                \
    const signed char* p_ = embT + (size_t)(T) * TILE_B + lane * 16;           \
    dst[0] = *(const int4v*)(p_);                                              \
    dst[1] = *(const int4v*)(p_ + 1024);                                       \
    dst[2] = *(const int4v*)(p_ + 2048);                                       \
    dst[3] = *(const int4v*)(p_ + 3072);                                       \
    enr    = *(const int*)(embT + (size_t)(T) * TILE_B + 4096 + lrow * 4);     \
  } while (0)
#define WAITV(n) asm volatile("s_waitcnt vmcnt(" #n ")" ::: "memory")

  int4v b0[4], b1[4], b2[4], b3[4];
  int   e0, e1, e2, e3;
  BLOAD(b0, e0, TIX(0)); BLOAD(b1, e1, TIX(1));
  BLOAD(b2, e2, TIX(2)); BLOAD(b3, e3, TIX(3));

  int bk[2][4];
  #pragma unroll
  for (int r = 0; r < 4; ++r) { bk[0][r] = INT_MAX; bk[1][r] = INT_MAX; }

  // K-split COMPUTE: 4 independent 2-deep MFMA chains, then integer combine.
#define COMPUTE(b, enr, T) do {                                                \
    int4v ci = {enr, enr, enr, enr};                                           \
    int4v zi = {0, 0, 0, 0};                                                   \
    int4v p0 = ci, q0 = zi, p1 = ci, q1 = zi;                                  \
    p0 = __builtin_amdgcn_mfma_i32_16x16x64_i8(a[0][0], b[0], p0, 0, 0, 0);    \
    q0 = __builtin_amdgcn_mfma_i32_16x16x64_i8(a[0][1], b[1], q0, 0, 0, 0);    \
    p1 = __builtin_amdgcn_mfma_i32_16x16x64_i8(a[1][0], b[0], p1, 0, 0, 0);    \
    q1 = __builtin_amdgcn_mfma_i32_16x16x64_i8(a[1][1], b[1], q1, 0, 0, 0);    \
    p0 = __builtin_amdgcn_mfma_i32_16x16x64_i8(a[0][2], b[2], p0, 0, 0, 0);    \
    q0 = __builtin_amdgcn_mfma_i32_16x16x64_i8(a[0][3], b[3], q0, 0, 0, 0);    \
    p1 = __builtin_amdgcn_mfma_i32_16x16x64_i8(a[1][2], b[2], p1, 0, 0, 0);    \
    q1 = __builtin_amdgcn_mfma_i32_16x16x64_i8(a[1][3], b[3], q1, 0, 0, 0);    \
    const int cd_ = (T) * 16 + lrow;                                           \
    _Pragma("unroll")                                                          \
    for (int r_ = 0; r_ < 4; ++r_) {                                           \
      const int s0_ = p0[r_] + q0[r_];                                         \
      const int s1_ = p1[r_] + q1[r_];                                         \
      bk[0][r_] = min(bk[0][r_], ((s0_ >> 2) << 10) | cd_);                    \
      bk[1][r_] = min(bk[1][r_], ((s1_ >> 2) << 10) | cd_);                    \
    }                                                                          \
  } while (0)

  for (int it = 0; it < 60; it += 4) {
    WAITV(15); COMPUTE(b0, e0, TIX(it + 0)); if (it < 56) BLOAD(b0, e0, TIX(it + 4));
    WAITV(15); COMPUTE(b1, e1, TIX(it + 1)); if (it < 56) BLOAD(b1, e1, TIX(it + 5));
    WAITV(15); COMPUTE(b2, e2, TIX(it + 2)); if (it < 56) BLOAD(b2, e2, TIX(it + 6));
    WAITV(15); COMPUTE(b3, e3, TIX(it + 3)); if (it < 56) BLOAD(b3, e3, TIX(it + 7));
  }
  WAITV(15); COMPUTE(b0, e0, TIX(60));
  WAITV(10); COMPUTE(b1, e1, TIX(61));
  WAITV(5);  COMPUTE(b2, e2, TIX(62));
  WAITV(0);  COMPUTE(b3, e3, TIX(63));
#undef COMPUTE
#undef BLOAD
#undef WAITV
#undef TIX

  // ---- cross-lane argmin: min over the 16 code columns ---------------------
  #pragma unroll
  for (int m = 1; m < 16; m <<= 1)
    #pragma unroll
    for (int g = 0; g < 2; ++g)
      #pragma unroll
      for (int r = 0; r < 4; ++r)
        bk[g][r] = min(bk[g][r], __shfl_xor(bk[g][r], m));
  if (lrow == 0)
    #pragma unroll
    for (int g = 0; g < 2; ++g)
      #pragma unroll
      for (int r = 0; r < 4; ++r)
        keyl[wv * 32 + g * 16 + lk * 4 + r] = bk[g][r];   // D row = lk*4 + r
  // same-wave LDS write->read: ordered by lgkmcnt, no barrier.

  // ---- fused epilogue: gather z_q rows for this wave's 32 tokens -----------
  const float4* emb4 = (const float4*)emb;
  float4*       out4 = (float4*)out;
  const size_t outBase = (size_t)blk * 128 + wv * 32;
  #pragma unroll 8
  for (int t2 = 0; t2 < 32; ++t2) {
    const int ci = keyl[wv * 32 + t2] & 1023;
    out4[(outBase + t2) * 64 + lane] = emb4[(size_t)ci * 64 + lane];
  }

  // ---- per-wave loss partial ----------------------------------------------
  const int tok = wv * 32 + (lane & 31);
  const int key = keyl[tok];
  const float sbest = (float)((key >> 10) << 2) * ABSC2F;   // en - 2 z.e
  float lt = (znl[tok] + sbest) * 0.5f;   // each token counted twice
  #pragma unroll
  for (int m = 1; m < 64; m <<= 1) lt += __shfl_xor(lt, m);
  if (lane == 0) partials[blk * 4 + wv] = lt;
}

// ---------------------------------------------------------------------------
// Final deterministic loss reduction: 2048 partials -> scalar
// ---------------------------------------------------------------------------
__global__ __launch_bounds__(256) void vq_loss(const float* __restrict__ partials,
                                               float* __restrict__ lossOut) {
  const int tid = threadIdx.x;
  float v = 0.f;
  #pragma unroll
  for (int i = 0; i < 8; ++i) v += partials[tid + i * 256];
  #pragma unroll
  for (int m = 1; m < 64; m <<= 1) v += __shfl_xor(v, m);
  __shared__ float ws2[4];
  if ((tid & 63) == 0) ws2[tid >> 6] = v;
  __syncthreads();
  if (tid == 0)
    lossOut[0] = (ws2[0] + ws2[1] + ws2[2] + ws2[3]) * (1.25f / 16777216.f);
}

extern "C" void kernel_launch(void* const* d_in, const int* in_sizes, int n_in,
                              void* d_out, int out_size, void* d_ws, size_t ws_size,
                              hipStream_t stream) {
  const float* z   = (const float*)d_in[0];   // 65536 x 256 fp32
  const float* emb = (const float*)d_in[1];   // 1024 x 256 fp32
  float* out = (float*)d_out;                 // 16777216 + 1 fp32

  char* ws = (char*)d_ws;
  signed char* embT  = (signed char*)ws;             // 266240 B
  float*       parts = (float*)(ws + (272 << 10));   // 8 KB

  vq_prep<<<N_E, 256, 0, stream>>>(emb, embT);
  vq_main<<<N_TOKS / 128, 256, 0, stream>>>(z, embT, emb, out, parts);
  vq_loss<<<1, 256, 0, stream>>>(parts, out + (size_t)N_TOKS * E_DIM);
}

// Round 14
// 47.494 us; speedup vs baseline: 2.0869x; 1.0165x over previous
//
#include <hip/hip_runtime.h>
#include <float.h>
#include <limits.h>

typedef __attribute__((ext_vector_type(4))) int int4v;

#define N_E   1024
#define E_DIM 256
#define N_TOKS 65536

#define SZF 21.166666f            // 127/6  (z scale, clamp at 6 sigma)
#define SEF 130048.0f             // 127*1024 (emb scale; |emb|<=1/1024)
#define ABSC2F (2.0f / (21.166666f * 130048.0f))   // s_real = s_int * ABSC2F

// ---------------------------------------------------------------------------
// Prep: emb fp32 -> i8 B-frag tiles (packed 4096 B) + separate en_int array.
// payload byte = tile*4096 + m*1024 + kq*256 + c16*16 + j  (k = m*64+kq*16+j)
// ---------------------------------------------------------------------------
__global__ __launch_bounds__(256) void vq_prep(const float* __restrict__ emb,
                                               signed char* __restrict__ pay,
                                               int* __restrict__ en_int) {
  const int code = blockIdx.x;
  const int t    = threadIdx.x;
  float v = emb[(size_t)code * E_DIM + t];
  int q = __float2int_rn(v * SEF);
  q = q > 127 ? 127 : (q < -127 ? -127 : q);
  const int m = t >> 6, kq = (t >> 4) & 3, j = t & 15;
  pay[(size_t)(code >> 4) * 4096 + m * 1024 + kq * 256 + (code & 15) * 16 + j] =
      (signed char)q;
  float sq = v * v;
  #pragma unroll
  for (int s = 1; s < 64; s <<= 1) sq += __shfl_xor(sq, s);
  __shared__ float ws3[4];
  if ((t & 63) == 0) ws3[t >> 6] = sq;
  __syncthreads();
  if (t == 0)
    en_int[code] = __float2int_rn((ws3[0] + ws3[1] + ws3[2] + ws3[3]) / ABSC2F);
}

// ---------------------------------------------------------------------------
// Main: 512 blocks x 4 waves, 32 tok/wave. Codebook lives in LDS:
// 8 chunks of 8 tiles (32 KB) double-buffered via global_load_lds, staged
// one chunk ahead; compute reads B-frags with contiguous ds_read_b128
// (conflict-free). en staged once to LDS (4 KB). 8 vmcnt(0)+barrier total.
// COMPUTE identical to R13 (k-split, acc init = en, int-key argmin).
// ---------------------------------------------------------------------------
__global__ __launch_bounds__(256, 2) void vq_main(
    const float* __restrict__ z, const signed char* __restrict__ pay,
    const int* __restrict__ en_int, const float* __restrict__ emb,
    float* __restrict__ out, float* __restrict__ partials) {
  __shared__ signed char ldsb[2][32768];   // 2 x 8-tile chunks
  __shared__ int   enlds[N_E];             // 4 KB
  __shared__ float znl[128];
  __shared__ int   keyl[128];

  const int tid = threadIdx.x, lane = tid & 63, wv = tid >> 6;
  const int blk = blockIdx.x, lrow = lane & 15, lk = lane >> 4;

  // ---- stage en (once) + chunk 0 into buf 0 (DMA, in flight under z phase) -
  {
    // en: wave wv stages bytes [wv*1024, wv*1024+1024)
    __builtin_amdgcn_global_load_lds(
        (const __attribute__((address_space(1))) void*)((const char*)en_int + wv * 1024 + lane * 16),
        (__attribute__((address_space(3))) void*)((char*)enlds + wv * 1024), 16, 0, 0);
    // chunk 0 payload: wave wv stages 8 KB
    #pragma unroll
    for (int i = 0; i < 8; ++i)
      __builtin_amdgcn_global_load_lds(
          (const __attribute__((address_space(1))) void*)(pay + wv * 8192 + i * 1024 + lane * 16),
          (__attribute__((address_space(3))) void*)(&ldsb[0][wv * 8192 + i * 1024]), 16, 0, 0);
  }

  // ---- z -> negated i8 A-frags + exact fp32 znorm --------------------------
  int4v a[2][4];
  #pragma unroll
  for (int g = 0; g < 2; ++g) {
    const float* zp = z + (size_t)(blk * 128 + wv * 32 + g * 16 + lrow) * E_DIM + lk * 16;
    float zn = 0.f;
    #pragma unroll
    for (int m = 0; m < 4; ++m) {
      int4v pk;
      #pragma unroll
      for (int d = 0; d < 4; ++d) {
        float4 f = *(const float4*)(zp + m * 64 + d * 4);
        zn += f.x * f.x + f.y * f.y + f.z * f.z + f.w * f.w;
        int q0 = __float2int_rn(fminf(fmaxf(f.x * -SZF, -127.f), 127.f));
        int q1 = __float2int_rn(fminf(fmaxf(f.y * -SZF, -127.f), 127.f));
        int q2 = __float2int_rn(fminf(fmaxf(f.z * -SZF, -127.f), 127.f));
        int q3 = __float2int_rn(fminf(fmaxf(f.w * -SZF, -127.f), 127.f));
        pk[d] = (q0 & 255) | ((q1 & 255) << 8) | ((q2 & 255) << 16) | ((q3 & 255) << 24);
      }
      a[g][m] = pk;
    }
    zn += __shfl_xor(zn, 16);
    zn += __shfl_xor(zn, 32);
    if (lk == 0) znl[wv * 32 + g * 16 + lrow] = zn;
  }

  __syncthreads();   // drains en + chunk-0 DMA + znl writes

  int bk[2][4];
  #pragma unroll
  for (int r = 0; r < 4; ++r) { bk[0][r] = INT_MAX; bk[1][r] = INT_MAX; }

#define STAGE_CHUNK(BUF, C) do {                                               \
    const signed char* gs_ = pay + (size_t)(C) * 32768 + wv * 8192 + lane * 16;\
    _Pragma("unroll")                                                          \
    for (int i_ = 0; i_ < 8; ++i_)                                             \
      __builtin_amdgcn_global_load_lds(                                        \
          (const __attribute__((address_space(1))) void*)(gs_ + i_ * 1024),    \
          (__attribute__((address_space(3))) void*)(&ldsb[(BUF)][wv * 8192 + i_ * 1024]), \
          16, 0, 0);                                                           \
  } while (0)

  // K-split COMPUTE (R13): 4 independent 2-deep MFMA chains, int-key argmin.
#define COMPUTE(BUF, TLOC, T) do {                                             \
    const int4v* bp_ = (const int4v*)&ldsb[(BUF)][(TLOC) * 4096 + lane * 16];  \
    int4v bb0 = bp_[0], bb1 = bp_[64], bb2 = bp_[128], bb3 = bp_[192];         \
    const int enr_ = enlds[(T) * 16 + lrow];                                   \
    int4v ci = {enr_, enr_, enr_, enr_};                                       \
    int4v zi = {0, 0, 0, 0};                                                   \
    int4v p0 = ci, q0 = zi, p1 = ci, q1 = zi;                                  \
    p0 = __builtin_amdgcn_mfma_i32_16x16x64_i8(a[0][0], bb0, p0, 0, 0, 0);     \
    q0 = __builtin_amdgcn_mfma_i32_16x16x64_i8(a[0][1], bb1, q0, 0, 0, 0);     \
    p1 = __builtin_amdgcn_mfma_i32_16x16x64_i8(a[1][0], bb0, p1, 0, 0, 0);     \
    q1 = __builtin_amdgcn_mfma_i32_16x16x64_i8(a[1][1], bb1, q1, 0, 0, 0);     \
    p0 = __builtin_amdgcn_mfma_i32_16x16x64_i8(a[0][2], bb2, p0, 0, 0, 0);     \
    q0 = __builtin_amdgcn_mfma_i32_16x16x64_i8(a[0][3], bb3, q0, 0, 0, 0);     \
    p1 = __builtin_amdgcn_mfma_i32_16x16x64_i8(a[1][2], bb2, p1, 0, 0, 0);     \
    q1 = __builtin_amdgcn_mfma_i32_16x16x64_i8(a[1][3], bb3, q1, 0, 0, 0);     \
    const int cd_ = (T) * 16 + lrow;                                           \
    _Pragma("unroll")                                                          \
    for (int r_ = 0; r_ < 4; ++r_) {                                           \
      const int s0_ = p0[r_] + q0[r_];                                         \
      const int s1_ = p1[r_] + q1[r_];                                         \
      bk[0][r_] = min(bk[0][r_], ((s0_ >> 2) << 10) | cd_);                    \
      bk[1][r_] = min(bk[1][r_], ((s1_ >> 2) << 10) | cd_);                    \
    }                                                                          \
  } while (0)

  #pragma unroll
  for (int c = 0; c < 8; ++c) {
    if (c < 7) STAGE_CHUNK((c + 1) & 1, c + 1);
    #pragma unroll
    for (int t = 0; t < 8; ++t)
      COMPUTE(c & 1, t, c * 8 + t);
    asm volatile("s_waitcnt vmcnt(0)" ::: "memory");   // next chunk landed
    __builtin_amdgcn_s_barrier();
  }
#undef COMPUTE
#undef STAGE_CHUNK

  // ---- cross-lane argmin: min over the 16 code columns ---------------------
  #pragma unroll
  for (int m = 1; m < 16; m <<= 1)
    #pragma unroll
    for (int g = 0; g < 2; ++g)
      #pragma unroll
      for (int r = 0; r < 4; ++r)
        bk[g][r] = min(bk[g][r], __shfl_xor(bk[g][r], m));
  if (lrow == 0)
    #pragma unroll
    for (int g = 0; g < 2; ++g)
      #pragma unroll
      for (int r = 0; r < 4; ++r)
        keyl[wv * 32 + g * 16 + lk * 4 + r] = bk[g][r];   // D row = lk*4 + r
  // same-wave LDS write->read: ordered by lgkmcnt, no barrier.

  // ---- fused epilogue: gather z_q rows for this wave's 32 tokens -----------
  const float4* emb4 = (const float4*)emb;
  float4*       out4 = (float4*)out;
  const size_t outBase = (size_t)blk * 128 + wv * 32;
  #pragma unroll 8
  for (int t2 = 0; t2 < 32; ++t2) {
    const int ci = keyl[wv * 32 + t2] & 1023;
    out4[(outBase + t2) * 64 + lane] = emb4[(size_t)ci * 64 + lane];
  }

  // ---- per-wave loss partial ----------------------------------------------
  const int tok = wv * 32 + (lane & 31);
  const int key = keyl[tok];
  const float sbest = (float)((key >> 10) << 2) * ABSC2F;   // en - 2 z.e
  float lt = (znl[tok] + sbest) * 0.5f;   // each token counted twice
  #pragma unroll
  for (int m = 1; m < 64; m <<= 1) lt += __shfl_xor(lt, m);
  if (lane == 0) partials[blk * 4 + wv] = lt;
}

// ---------------------------------------------------------------------------
// Final deterministic loss reduction: 2048 partials -> scalar
// ---------------------------------------------------------------------------
__global__ __launch_bounds__(256) void vq_loss(const float* __restrict__ partials,
                                               float* __restrict__ lossOut) {
  const int tid = threadIdx.x;
  float v = 0.f;
  #pragma unroll
  for (int i = 0; i < 8; ++i) v += partials[tid + i * 256];
  #pragma unroll
  for (int m = 1; m < 64; m <<= 1) v += __shfl_xor(v, m);
  __shared__ float ws2[4];
  if ((tid & 63) == 0) ws2[tid >> 6] = v;
  __syncthreads();
  if (tid == 0)
    lossOut[0] = (ws2[0] + ws2[1] + ws2[2] + ws2[3]) * (1.25f / 16777216.f);
}

extern "C" void kernel_launch(void* const* d_in, const int* in_sizes, int n_in,
                              void* d_out, int out_size, void* d_ws, size_t ws_size,
                              hipStream_t stream) {
  const float* z   = (const float*)d_in[0];   // 65536 x 256 fp32
  const float* emb = (const float*)d_in[1];   // 1024 x 256 fp32
  float* out = (float*)d_out;                 // 16777216 + 1 fp32

  char* ws = (char*)d_ws;
  signed char* pay   = (signed char*)ws;             // 256 KB payload tiles
  int*         enint = (int*)  (ws + (256 << 10));   // 4 KB
  float*       parts = (float*)(ws + (260 << 10));   // 8 KB

  vq_prep<<<N_E, 256, 0, stream>>>(emb, pay, enint);
  vq_main<<<N_TOKS / 128, 256, 0, stream>>>(z, pay, enint, emb, out, parts);
  vq_loss<<<1, 256, 0, stream>>>(parts, out + (size_t)N_TOKS * E_DIM);
}